// Round 3
// baseline (1106.496 us; speedup 1.0000x reference)
//
#include <hip/hip_runtime.h>
#include <hip/hip_bf16.h>
#include <math.h>

// ODNet_att: 3×(graph-GRU with h0=0) + hidden-fusion + 2-head self-attention.
// Correctness-first round. One shared bf16 MFMA GEMM (128x128 tile, 4 waves,
// BK=64, reg-staged LDS) for all matmuls; CSR-based graph propagation; f32
// softmax. All activations bf16 (threshold 5.03e-2 is bf16-grade).
// Workspace peak: 216 MiB (buffers aliased by lifetime).

#define DEV __device__ __forceinline__

typedef __attribute__((ext_vector_type(4))) float  f32x4;
typedef __attribute__((ext_vector_type(4))) float  fvec4;
typedef __attribute__((ext_vector_type(8))) short  bf16x8;
typedef __attribute__((ext_vector_type(4))) unsigned short u16x4;

constexpr int BN_ = 32768;     // B*N = 64*512
constexpr int E_  = 262144;    // edges
constexpr long OUTSEC = 4194304; // 32768*128 per output section

DEV unsigned short f2bf(float f){
  union { float f; unsigned u; } v; v.f = f;
  unsigned r = (v.u + 0x7FFFu + ((v.u >> 16) & 1u)) >> 16;
  return (unsigned short)r;
}
DEV float b2f(unsigned short h){
  union { unsigned u; float f; } v; v.u = ((unsigned)h) << 16;
  return v.f;
}

// ---------------- graph build ----------------
__global__ __launch_bounds__(256) void histdeg_kernel(const int* __restrict__ ei,
    const float* __restrict__ ew, unsigned* __restrict__ cnt, float* __restrict__ deg){
  int e = blockIdx.x*256 + threadIdx.x;
  int d = ei[E_ + e];
  atomicAdd(&cnt[d], 1u);
  atomicAdd(&deg[d], ew[e]);
}

__global__ __launch_bounds__(1024) void scan_kernel(const unsigned* __restrict__ cnt,
                                                    unsigned* __restrict__ rowptr){
  __shared__ unsigned sm[1024];
  __shared__ unsigned carry;
  int tid = threadIdx.x;
  if (tid == 0) carry = 0;
  __syncthreads();
  for (int base = 0; base < BN_; base += 1024){
    unsigned v = cnt[base + tid];
    sm[tid] = v;
    __syncthreads();
    for (int off = 1; off < 1024; off <<= 1){
      unsigned t = (tid >= off) ? sm[tid - off] : 0u;
      __syncthreads();
      sm[tid] += t;
      __syncthreads();
    }
    rowptr[base + tid] = carry + sm[tid] - v;  // exclusive prefix
    __syncthreads();
    if (tid == 1023) carry += sm[1023];
    __syncthreads();
  }
  if (tid == 0) rowptr[BN_] = carry;
}

__global__ __launch_bounds__(256) void scatter_kernel(const int* __restrict__ ei,
    const float* __restrict__ ew, const unsigned* __restrict__ rowptr,
    unsigned* __restrict__ curs, unsigned* __restrict__ csrc, float* __restrict__ csrw){
  int e = blockIdx.x*256 + threadIdx.x;
  int d = ei[E_ + e];
  unsigned pos = atomicAdd(&curs[d], 1u);
  unsigned idx = rowptr[d] + pos;
  csrc[idx] = (unsigned)ei[e];
  csrw[idx] = ew[e];
}

// ---------------- propagation: one wave per node, 4 feats/lane ----------------
template<int SRC>  // 0: read f32 input, 1: read bf16 from zcat (pre-offset ptr)
__global__ __launch_bounds__(256) void prop_kernel(const float* __restrict__ xf,
    const unsigned short* __restrict__ zin, unsigned short* __restrict__ zout,
    const unsigned* __restrict__ rowptr, const unsigned* __restrict__ csrc,
    const float* __restrict__ csrw, const float* __restrict__ deg){
  int node = blockIdx.x*4 + (threadIdx.x >> 6);
  int l = threadIdx.x & 63;
  unsigned b0 = rowptr[node], b1 = rowptr[node + 1];
  float a0 = 0.f, a1 = 0.f, a2 = 0.f, a3 = 0.f;
  for (unsigned e = b0; e < b1; ++e){
    int s = csrc[e]; float w = csrw[e];
    if constexpr (SRC == 0){
      fvec4 v = *(const fvec4*)(xf + (long)s*256 + l*4);
      a0 += w*v[0]; a1 += w*v[1]; a2 += w*v[2]; a3 += w*v[3];
    } else {
      u16x4 v = *(const u16x4*)(zin + (long)s*768 + l*4);
      a0 += w*b2f(v[0]); a1 += w*b2f(v[1]); a2 += w*b2f(v[2]); a3 += w*b2f(v[3]);
    }
  }
  float dg = deg[node]; dg = dg > 1.f ? dg : 1.f;
  float inv = 1.f / dg;
  u16x4 o = { f2bf(a0*inv), f2bf(a1*inv), f2bf(a2*inv), f2bf(a3*inv) };
  *(u16x4*)(zout + (long)node*768 + l*4) = o;
}

// x (f32 [BN][256]) -> zcat cols 0:256 (bf16, row stride 768)
__global__ __launch_bounds__(256) void convx_kernel(const float* __restrict__ xf,
                                                    unsigned short* __restrict__ zcat){
  int id = blockIdx.x*256 + threadIdx.x;   // over 32768*64
  fvec4 v = ((const fvec4*)xf)[id];
  int m = id >> 6, c4 = id & 63;
  u16x4 o = { f2bf(v[0]), f2bf(v[1]), f2bf(v[2]), f2bf(v[3]) };
  *(u16x4*)(zcat + (long)m*768 + c4*4) = o;
}

// ---------------- weight prep ----------------
__global__ __launch_bounds__(256) void cvt_f2b_kernel(const float* __restrict__ s,
                                                      unsigned short* __restrict__ d, int n){
  int i = blockIdx.x*256 + threadIdx.x;
  if (i < n) d[i] = f2bf(s[i]);
}

// Build BT[256][768]: cols 0:128 = u-part of W_ru (cols 128:256), 128:256 = W_c.
// k -> W row (k>>8)*384 + (k&255)  (only x-rows of each hop block matter; h==0).
__global__ __launch_bounds__(256) void weff_kernel(const float* __restrict__ Wru,
    const float* __restrict__ bru, const float* __restrict__ Wc, const float* __restrict__ bc,
    unsigned short* __restrict__ Weff, float* __restrict__ beff){
  int id = blockIdx.x*256 + threadIdx.x;   // 256*768
  int n = id / 768, k = id % 768;
  int row = (k >> 8)*384 + (k & 255);
  float w = (n < 128) ? Wru[(long)row*256 + 128 + n] : Wc[(long)row*128 + (n - 128)];
  Weff[(long)n*768 + k] = f2bf(w);
  if (k == 0) beff[n] = (n < 128) ? bru[128 + n] : bc[n - 128];
}

__global__ __launch_bounds__(256) void pe_kernel(float* __restrict__ pe){
  int id = blockIdx.x*256 + threadIdx.x;   // 64*512
  int b = id >> 9, o = id & 511;
  float j2 = (float)(o & ~1);
  float ang = (float)b * expf(-j2 * (9.210340371976184f / 512.f)); // ln(1e4)
  pe[id] = (o & 1) ? cosf(ang) : sinf(ang);
}

// ---------------- shared bf16 MFMA GEMM ----------------
// C[m][n] = scale * sum_k A[m][k]*Bt[n][k] (+bias[n]) (+pe)  ; tiles 128x128, BK=64.
// MODE 0: plain (z-batch via sA/sB/sC).  MODE 1: attention scores (A=Q,Bt=K from qkv).
// MODE 2: ctx (A=P chunk-local, Bt=vT per pair, C scattered into ctx).
// EPI 0: f32 store. 2: bf16 store. 3: bf16 + pos-enc. 4: f32 store with row remap
//        (n,b)->(b*512+n) into d_out (final gated output).
template<int MODE, int EPI>
__global__ __launch_bounds__(256) void gemm_bt(
    const unsigned short* __restrict__ A, const unsigned short* __restrict__ Bt,
    float* __restrict__ Cf, unsigned short* __restrict__ Cb,
    int Ktot, int lda, int ldb, int ldc,
    long sA, long sB, long sC, int g0,
    const float* __restrict__ bias, const float* __restrict__ pe, float scale)
{
  __shared__ unsigned short As[128*64];
  __shared__ unsigned short Bs[128*64];
  const int tid = threadIdx.x;
  long aOff, bOff, cOff;
  if constexpr (MODE == 0){
    aOff = blockIdx.z * sA; bOff = blockIdx.z * sB; cOff = blockIdx.z * sC;
  } else if constexpr (MODE == 1){
    int g = g0 + blockIdx.z;
    long base = (long)(g >> 1)*1536 + (long)(g & 1)*256;
    aOff = base; bOff = base + 512; cOff = (long)blockIdx.z * 262144;
  } else {
    int g = g0 + blockIdx.z;
    aOff = (long)blockIdx.z * 262144;
    bOff = (long)g * 131072;
    cOff = (long)g * 256;
  }
  const int bm = blockIdx.y * 128, bn = blockIdx.x * 128;
  const int w = tid >> 6, l = tid & 63;
  const int wr = w >> 1, wc = w & 1;
  f32x4 acc[4][4] = {};
  for (int kt = 0; kt < Ktot; kt += 64){
    #pragma unroll
    for (int i = 0; i < 4; ++i){
      int c = tid + i*256;
      int row = c >> 3, gg = c & 7;
      *(bf16x8*)(&As[c*8]) = *(const bf16x8*)(A  + aOff + (long)(bm + row)*lda + kt + gg*8);
      *(bf16x8*)(&Bs[c*8]) = *(const bf16x8*)(Bt + bOff + (long)(bn + row)*ldb + kt + gg*8);
    }
    __syncthreads();
    #pragma unroll
    for (int ks = 0; ks < 2; ++ks){
      bf16x8 aF[4], bF[4];
      #pragma unroll
      for (int mi = 0; mi < 4; ++mi)
        aF[mi] = *(const bf16x8*)(&As[(wr*64 + mi*16 + (l & 15))*64 + ks*32 + (l >> 4)*8]);
      #pragma unroll
      for (int ni = 0; ni < 4; ++ni)
        bF[ni] = *(const bf16x8*)(&Bs[(wc*64 + ni*16 + (l & 15))*64 + ks*32 + (l >> 4)*8]);
      #pragma unroll
      for (int mi = 0; mi < 4; ++mi)
        #pragma unroll
        for (int ni = 0; ni < 4; ++ni)
          acc[mi][ni] = __builtin_amdgcn_mfma_f32_16x16x32_bf16(aF[mi], bF[ni], acc[mi][ni], 0, 0, 0);
    }
    __syncthreads();
  }
  // D layout: col = lane&15, row = (lane>>4)*4 + j  (m89-verified)
  #pragma unroll
  for (int mi = 0; mi < 4; ++mi){
    #pragma unroll
    for (int ni = 0; ni < 4; ++ni){
      int col = bn + wc*64 + ni*16 + (l & 15);
      int row0 = bm + wr*64 + mi*16 + ((l >> 4) << 2);
      #pragma unroll
      for (int j = 0; j < 4; ++j){
        int row = row0 + j;
        float v = acc[mi][ni][j] * scale;
        if (bias) v += bias[col];
        if constexpr (EPI == 3) v += pe[((row & 63) << 9) + col];
        if constexpr (EPI == 0){
          Cf[cOff + (long)row*ldc + col] = v;
        } else if constexpr (EPI == 4){
          long orow = (long)(row & 63)*512 + (row >> 6);
          Cf[orow*ldc + col] = v;
        } else {
          Cb[cOff + (long)row*ldc + col] = f2bf(v);
        }
      }
    }
  }
}

// ---------------- epilogues / glue ----------------
__global__ __launch_bounds__(256) void ucepi_kernel(const unsigned short* __restrict__ uc,
                                                    float* __restrict__ outp){
  int id = blockIdx.x*256 + threadIdx.x;   // 32768*128
  int m = id >> 7, n = id & 127;
  float ul = b2f(uc[(long)m*256 + n]);
  float cl = b2f(uc[(long)m*256 + 128 + n]);
  float u = 1.f / (1.f + expf(-ul));
  outp[id] = (1.f - u) * tanhf(cl);
}

// Afus[(n*64+b)][c] = fusion[b,c,n] = concat([hs,hl])[b*512 + 2c + (n>>8), n&255]
__global__ __launch_bounds__(256) void afus_kernel(const float* __restrict__ out,
                                                   unsigned short* __restrict__ Afus){
  int rc = blockIdx.x, a = blockIdx.y, b = blockIdx.z;
  int c = threadIdx.x;  // 0..255
  const float* hsrc = out + 2*OUTSEC;   // hs
  const float* hlrc = out + 1*OUTSEC;   // hl
  long rowb = (long)b*512 + 2*c + a;
  #pragma unroll 4
  for (int r0 = 0; r0 < 32; ++r0){
    int r = rc*32 + r0;
    float v = (r < 128) ? hsrc[rowb*128 + r] : hlrc[rowb*128 + (r - 128)];
    long mrow = (long)(a*256 + r)*64 + b;
    Afus[mrow*256 + c] = f2bf(v);
  }
}

// vT[g=(b,h)][d][t] = qkv[t*64+b][1024 + h*256 + d]  (64x64 LDS transpose tiles)
__global__ __launch_bounds__(256) void vt_kernel(const unsigned short* __restrict__ qkv,
                                                 unsigned short* __restrict__ vT){
  int g = blockIdx.y; int b = g >> 1, h = g & 1;
  int tt = blockIdx.x & 7, dt = blockIdx.x >> 3;
  __shared__ unsigned short sm[64][65];
  int lrow = threadIdx.x >> 6, lcol = threadIdx.x & 63;
  const unsigned short* src = qkv + (long)b*1536 + 1024 + (long)h*256 + dt*64;
  #pragma unroll
  for (int i = 0; i < 16; ++i){
    int t = tt*64 + lrow + i*4;
    sm[lrow + i*4][lcol] = src[(long)t*98304 + lcol];
  }
  __syncthreads();
  unsigned short* dstp = vT + (long)g*131072 + (long)(dt*64)*512 + tt*64;
  #pragma unroll
  for (int i = 0; i < 16; ++i){
    int d = lrow + i*4;
    dstp[(long)d*512 + lcol] = sm[lcol][d];
  }
}

__global__ __launch_bounds__(256) void softmax_kernel(const float* __restrict__ S,
                                                      unsigned short* __restrict__ P){
  int row = blockIdx.x*4 + (threadIdx.x >> 6);
  int l = threadIdx.x & 63;
  const fvec4* sr = (const fvec4*)(S + (long)row*512);
  fvec4 v0 = sr[l], v1 = sr[l + 64];
  float m = fmaxf(fmaxf(fmaxf(v0[0],v0[1]), fmaxf(v0[2],v0[3])),
                  fmaxf(fmaxf(v1[0],v1[1]), fmaxf(v1[2],v1[3])));
  #pragma unroll
  for (int off = 32; off; off >>= 1) m = fmaxf(m, __shfl_xor(m, off));
  float e0[4], e1[4], s = 0.f;
  #pragma unroll
  for (int j = 0; j < 4; ++j){ e0[j] = expf(v0[j]-m); s += e0[j]; }
  #pragma unroll
  for (int j = 0; j < 4; ++j){ e1[j] = expf(v1[j]-m); s += e1[j]; }
  #pragma unroll
  for (int off = 32; off; off >>= 1) s += __shfl_xor(s, off);
  float inv = 1.f / s;
  u16x4 p0 = { f2bf(e0[0]*inv), f2bf(e0[1]*inv), f2bf(e0[2]*inv), f2bf(e0[3]*inv) };
  u16x4 p1 = { f2bf(e1[0]*inv), f2bf(e1[1]*inv), f2bf(e1[2]*inv), f2bf(e1[3]*inv) };
  *(u16x4*)(P + (long)row*512 + l*4) = p0;
  *(u16x4*)(P + (long)row*512 + 256 + l*4) = p1;
}

// ---------------- host ----------------
extern "C" void kernel_launch(void* const* d_in, const int* in_sizes, int n_in,
                              void* d_out, int out_size, void* d_ws, size_t ws_size,
                              hipStream_t stream)
{
  (void)in_sizes; (void)n_in; (void)out_size;
  constexpr long MB = 1l << 20;
  if (ws_size < 216*MB) return;  // layout needs 216 MiB; fail loudly via absmax

  const float* xin[3] = {(const float*)d_in[0], (const float*)d_in[1], (const float*)d_in[2]};
  const int*   ei = (const int*)d_in[3];
  const float* ew = (const float*)d_in[4];
  const float* Wru[3] = {(const float*)d_in[5], (const float*)d_in[9],  (const float*)d_in[13]};
  const float* bru[3] = {(const float*)d_in[6], (const float*)d_in[10], (const float*)d_in[14]};
  const float* Wc[3]  = {(const float*)d_in[7], (const float*)d_in[11], (const float*)d_in[15]};
  const float* bc[3]  = {(const float*)d_in[8], (const float*)d_in[12], (const float*)d_in[16]};
  const float* Whd  = (const float*)d_in[17]; const float* bhd   = (const float*)d_in[18];
  const float* Win  = (const float*)d_in[19]; const float* bin   = (const float*)d_in[20];
  const float* Wout = (const float*)d_in[21]; const float* bout  = (const float*)d_in[22];
  const float* Wgt  = (const float*)d_in[23]; const float* bgate = (const float*)d_in[24];
  float* out = (float*)d_out;
  char* ws = (char*)d_ws;

  float*    deg    = (float*)(ws + 0);
  unsigned* cnt    = (unsigned*)(ws + 131072);
  unsigned* rowptr = (unsigned*)(ws + 262144);
  unsigned* curs   = (unsigned*)(ws + 524288);
  unsigned* csrc   = (unsigned*)(ws + 786432);
  float*    csrw   = (float*)(ws + 1835008);
  unsigned short* Weff = (unsigned short*)(ws + 2883584);   // 3 x [256][768]
  float*    beff   = (float*)(ws + 4063232);                // 3 x 256
  unsigned short* WHD   = (unsigned short*)(ws + 4194304);  // [512][256]
  unsigned short* WIN   = (unsigned short*)(ws + 4456448);  // [1536][512]
  unsigned short* WOUTB = (unsigned short*)(ws + 6029312);  // [512][512]
  unsigned short* WGTB  = (unsigned short*)(ws + 6553600);  // [128][512]
  float*    PE     = (float*)(ws + 6684672);                // [64][512]
  unsigned short* XATT = (unsigned short*)(ws + 8*MB);      // [32768][512] (dies after qkv)
  unsigned short* ZCAT = (unsigned short*)(ws + 40*MB);     // [32768][768] (phase A)
  unsigned short* UC   = (unsigned short*)(ws + 88*MB);     // [32768][256] (phase A)
  unsigned short* AFUS = (unsigned short*)(ws + 40*MB);     // [32768][256] (phase B)
  unsigned short* QKV  = (unsigned short*)(ws + 40*MB);     // [32768][1536] (phase C+)
  unsigned short* VT   = (unsigned short*)(ws + 136*MB);    // [128][256][512]
  unsigned short* CTX  = (unsigned short*)(ws + 168*MB);    // [32768][512]
  float*    SCORES = (float*)(ws + 8*MB);                   // [32][512][512] (reuses XATT)
  unsigned short* PBUF = (unsigned short*)(ws + 200*MB);    // [32][512][512] bf16
  unsigned short* ATTO = (unsigned short*)(ws + 8*MB);      // [32768][512] (reuses SCORES)

  // graph build
  hipMemsetAsync(deg,  0, 131072, stream);
  hipMemsetAsync(cnt,  0, 131072, stream);
  hipMemsetAsync(curs, 0, 131072, stream);
  histdeg_kernel<<<1024, 256, 0, stream>>>(ei, ew, cnt, deg);
  scan_kernel<<<1, 1024, 0, stream>>>(cnt, rowptr);
  scatter_kernel<<<1024, 256, 0, stream>>>(ei, ew, rowptr, curs, csrc, csrw);

  // weight prep
  for (int br = 0; br < 3; ++br)
    weff_kernel<<<768, 256, 0, stream>>>(Wru[br], bru[br], Wc[br], bc[br],
                                         Weff + (long)br*196608, beff + br*256);
  cvt_f2b_kernel<<<512,  256, 0, stream>>>(Whd,  WHD,   131072);
  cvt_f2b_kernel<<<3072, 256, 0, stream>>>(Win,  WIN,   786432);
  cvt_f2b_kernel<<<1024, 256, 0, stream>>>(Wout, WOUTB, 262144);
  cvt_f2b_kernel<<<256,  256, 0, stream>>>(Wgt,  WGTB,  65536);
  pe_kernel<<<128, 256, 0, stream>>>(PE);

  // branches: hf (x_od), hl (history), hs (yesterday) -> out sections 0,1,2
  for (int br = 0; br < 3; ++br){
    convx_kernel<<<8192, 256, 0, stream>>>(xin[br], ZCAT);
    prop_kernel<0><<<8192, 256, 0, stream>>>(xin[br], nullptr, ZCAT + 256,
                                             rowptr, csrc, csrw, deg);
    prop_kernel<1><<<8192, 256, 0, stream>>>(nullptr, ZCAT + 256, ZCAT + 512,
                                             rowptr, csrc, csrw, deg);
    gemm_bt<0,2><<<dim3(2,256,1), 256, 0, stream>>>(ZCAT, Weff + (long)br*196608,
        nullptr, UC, 768, 768, 768, 256, 0,0,0, 0, beff + br*256, nullptr, 1.0f);
    ucepi_kernel<<<16384, 256, 0, stream>>>(UC, out + (long)br*OUTSEC);
  }

  // fusion gather + uh GEMM (bias + pos-enc fused) -> x_att bf16
  afus_kernel<<<dim3(8,2,64), 256, 0, stream>>>(out, AFUS);
  gemm_bt<0,3><<<dim3(4,256,1), 256, 0, stream>>>(AFUS, WHD, nullptr, XATT,
      256, 256, 256, 512, 0,0,0, 0, bhd, PE, 1.0f);

  // qkv
  gemm_bt<0,2><<<dim3(12,256,1), 256, 0, stream>>>(XATT, WIN, nullptr, QKV,
      512, 512, 512, 1536, 0,0,0, 0, bin, nullptr, 1.0f);
  vt_kernel<<<dim3(32,128), 256, 0, stream>>>(QKV, VT);

  // attention in 4 chunks of 32 (b,h) pairs
  for (int c4 = 0; c4 < 4; ++c4){
    gemm_bt<1,0><<<dim3(4,4,32), 256, 0, stream>>>(QKV, QKV, SCORES, nullptr,
        256, 98304, 98304, 512, 0,0,0, c4*32, nullptr, nullptr, 0.0625f);
    softmax_kernel<<<4096, 256, 0, stream>>>(SCORES, PBUF);
    gemm_bt<2,2><<<dim3(2,4,32), 256, 0, stream>>>(PBUF, VT, nullptr, CTX,
        512, 512, 512, 32768, 0,0,0, c4*32, nullptr, nullptr, 1.0f);
  }

  // attn_out and gated output (row remap (n,b) -> b*512+n fused into epilogue)
  gemm_bt<0,2><<<dim3(4,256,1), 256, 0, stream>>>(CTX, WOUTB, nullptr, ATTO,
      512, 512, 512, 512, 0,0,0, 0, bout, nullptr, 1.0f);
  gemm_bt<0,4><<<dim3(1,256,1), 256, 0, stream>>>(ATTO, WGTB, out + 3*OUTSEC, nullptr,
      512, 512, 512, 128, 0,0,0, 0, bgate, nullptr, 1.0f);
}

// Round 4
// 1094.101 us; speedup vs baseline: 1.0113x; 1.0113x over previous
//
#include <hip/hip_runtime.h>
#include <hip/hip_bf16.h>
#include <math.h>

// ODNet_att: 3×(graph-GRU with h0=0) + hidden-fusion + 2-head self-attention.
// R4: gemm_bt staging switched to global_load_lds width=16 (direct HBM->LDS,
// m97 lever). LDS layout unchanged (linear in lane order). Everything else
// identical to the R3 passing kernel.

#define DEV __device__ __forceinline__

typedef __attribute__((ext_vector_type(4))) float  f32x4;
typedef __attribute__((ext_vector_type(4))) float  fvec4;
typedef __attribute__((ext_vector_type(8))) short  bf16x8;
typedef __attribute__((ext_vector_type(4))) unsigned short u16x4;

constexpr int BN_ = 32768;     // B*N = 64*512
constexpr int E_  = 262144;    // edges
constexpr long OUTSEC = 4194304; // 32768*128 per output section

DEV unsigned short f2bf(float f){
  union { float f; unsigned u; } v; v.f = f;
  unsigned r = (v.u + 0x7FFFu + ((v.u >> 16) & 1u)) >> 16;
  return (unsigned short)r;
}
DEV float b2f(unsigned short h){
  union { unsigned u; float f; } v; v.u = ((unsigned)h) << 16;
  return v.f;
}

// ---------------- graph build ----------------
__global__ __launch_bounds__(256) void histdeg_kernel(const int* __restrict__ ei,
    const float* __restrict__ ew, unsigned* __restrict__ cnt, float* __restrict__ deg){
  int e = blockIdx.x*256 + threadIdx.x;
  int d = ei[E_ + e];
  atomicAdd(&cnt[d], 1u);
  atomicAdd(&deg[d], ew[e]);
}

__global__ __launch_bounds__(1024) void scan_kernel(const unsigned* __restrict__ cnt,
                                                    unsigned* __restrict__ rowptr){
  __shared__ unsigned sm[1024];
  __shared__ unsigned carry;
  int tid = threadIdx.x;
  if (tid == 0) carry = 0;
  __syncthreads();
  for (int base = 0; base < BN_; base += 1024){
    unsigned v = cnt[base + tid];
    sm[tid] = v;
    __syncthreads();
    for (int off = 1; off < 1024; off <<= 1){
      unsigned t = (tid >= off) ? sm[tid - off] : 0u;
      __syncthreads();
      sm[tid] += t;
      __syncthreads();
    }
    rowptr[base + tid] = carry + sm[tid] - v;  // exclusive prefix
    __syncthreads();
    if (tid == 1023) carry += sm[1023];
    __syncthreads();
  }
  if (tid == 0) rowptr[BN_] = carry;
}

__global__ __launch_bounds__(256) void scatter_kernel(const int* __restrict__ ei,
    const float* __restrict__ ew, const unsigned* __restrict__ rowptr,
    unsigned* __restrict__ curs, unsigned* __restrict__ csrc, float* __restrict__ csrw){
  int e = blockIdx.x*256 + threadIdx.x;
  int d = ei[E_ + e];
  unsigned pos = atomicAdd(&curs[d], 1u);
  unsigned idx = rowptr[d] + pos;
  csrc[idx] = (unsigned)ei[e];
  csrw[idx] = ew[e];
}

// ---------------- propagation: one wave per node, 4 feats/lane ----------------
template<int SRC>  // 0: read f32 input, 1: read bf16 from zcat (pre-offset ptr)
__global__ __launch_bounds__(256) void prop_kernel(const float* __restrict__ xf,
    const unsigned short* __restrict__ zin, unsigned short* __restrict__ zout,
    const unsigned* __restrict__ rowptr, const unsigned* __restrict__ csrc,
    const float* __restrict__ csrw, const float* __restrict__ deg){
  int node = blockIdx.x*4 + (threadIdx.x >> 6);
  int l = threadIdx.x & 63;
  unsigned b0 = rowptr[node], b1 = rowptr[node + 1];
  float a0 = 0.f, a1 = 0.f, a2 = 0.f, a3 = 0.f;
  for (unsigned e = b0; e < b1; ++e){
    int s = csrc[e]; float w = csrw[e];
    if constexpr (SRC == 0){
      fvec4 v = *(const fvec4*)(xf + (long)s*256 + l*4);
      a0 += w*v[0]; a1 += w*v[1]; a2 += w*v[2]; a3 += w*v[3];
    } else {
      u16x4 v = *(const u16x4*)(zin + (long)s*768 + l*4);
      a0 += w*b2f(v[0]); a1 += w*b2f(v[1]); a2 += w*b2f(v[2]); a3 += w*b2f(v[3]);
    }
  }
  float dg = deg[node]; dg = dg > 1.f ? dg : 1.f;
  float inv = 1.f / dg;
  u16x4 o = { f2bf(a0*inv), f2bf(a1*inv), f2bf(a2*inv), f2bf(a3*inv) };
  *(u16x4*)(zout + (long)node*768 + l*4) = o;
}

// x (f32 [BN][256]) -> zcat cols 0:256 (bf16, row stride 768)
__global__ __launch_bounds__(256) void convx_kernel(const float* __restrict__ xf,
                                                    unsigned short* __restrict__ zcat){
  int id = blockIdx.x*256 + threadIdx.x;   // over 32768*64
  fvec4 v = ((const fvec4*)xf)[id];
  int m = id >> 6, c4 = id & 63;
  u16x4 o = { f2bf(v[0]), f2bf(v[1]), f2bf(v[2]), f2bf(v[3]) };
  *(u16x4*)(zcat + (long)m*768 + c4*4) = o;
}

// ---------------- weight prep ----------------
__global__ __launch_bounds__(256) void cvt_f2b_kernel(const float* __restrict__ s,
                                                      unsigned short* __restrict__ d, int n){
  int i = blockIdx.x*256 + threadIdx.x;
  if (i < n) d[i] = f2bf(s[i]);
}

// Build BT[256][768]: cols 0:128 = u-part of W_ru (cols 128:256), 128:256 = W_c.
// k -> W row (k>>8)*384 + (k&255)  (only x-rows of each hop block matter; h==0).
__global__ __launch_bounds__(256) void weff_kernel(const float* __restrict__ Wru,
    const float* __restrict__ bru, const float* __restrict__ Wc, const float* __restrict__ bc,
    unsigned short* __restrict__ Weff, float* __restrict__ beff){
  int id = blockIdx.x*256 + threadIdx.x;   // 256*768
  int n = id / 768, k = id % 768;
  int row = (k >> 8)*384 + (k & 255);
  float w = (n < 128) ? Wru[(long)row*256 + 128 + n] : Wc[(long)row*128 + (n - 128)];
  Weff[(long)n*768 + k] = f2bf(w);
  if (k == 0) beff[n] = (n < 128) ? bru[128 + n] : bc[n - 128];
}

__global__ __launch_bounds__(256) void pe_kernel(float* __restrict__ pe){
  int id = blockIdx.x*256 + threadIdx.x;   // 64*512
  int b = id >> 9, o = id & 511;
  float j2 = (float)(o & ~1);
  float ang = (float)b * expf(-j2 * (9.210340371976184f / 512.f)); // ln(1e4)
  pe[id] = (o & 1) ? cosf(ang) : sinf(ang);
}

// ---------------- shared bf16 MFMA GEMM ----------------
// C[m][n] = scale * sum_k A[m][k]*Bt[n][k] (+bias[n]) (+pe)  ; tiles 128x128, BK=64.
// Staging: global_load_lds width=16 (linear LDS dest = lane order). MODE/EPI as R3.
template<int MODE, int EPI>
__global__ __launch_bounds__(256) void gemm_bt(
    const unsigned short* __restrict__ A, const unsigned short* __restrict__ Bt,
    float* __restrict__ Cf, unsigned short* __restrict__ Cb,
    int Ktot, int lda, int ldb, int ldc,
    long sA, long sB, long sC, int g0,
    const float* __restrict__ bias, const float* __restrict__ pe, float scale)
{
  __shared__ unsigned short As[128*64];
  __shared__ unsigned short Bs[128*64];
  const int tid = threadIdx.x;
  long aOff, bOff, cOff;
  if constexpr (MODE == 0){
    aOff = blockIdx.z * sA; bOff = blockIdx.z * sB; cOff = blockIdx.z * sC;
  } else if constexpr (MODE == 1){
    int g = g0 + blockIdx.z;
    long base = (long)(g >> 1)*1536 + (long)(g & 1)*256;
    aOff = base; bOff = base + 512; cOff = (long)blockIdx.z * 262144;
  } else {
    int g = g0 + blockIdx.z;
    aOff = (long)blockIdx.z * 262144;
    bOff = (long)g * 131072;
    cOff = (long)g * 256;
  }
  const int bm = blockIdx.y * 128, bn = blockIdx.x * 128;
  const int w = tid >> 6, l = tid & 63;
  const int wr = w >> 1, wc = w & 1;

  // per-lane global staging bases (element offsets); LDS dest is linear in c
  const unsigned short* aB[4];
  const unsigned short* bB[4];
  #pragma unroll
  for (int i = 0; i < 4; ++i){
    int c = tid + i*256;
    int row = c >> 3, gg = c & 7;
    aB[i] = A  + aOff + (long)(bm + row)*lda + gg*8;
    bB[i] = Bt + bOff + (long)(bn + row)*ldb + gg*8;
  }

  f32x4 acc[4][4] = {};
  for (int kt = 0; kt < Ktot; kt += 64){
    #pragma unroll
    for (int i = 0; i < 4; ++i){
      __builtin_amdgcn_global_load_lds(
        (const __attribute__((address_space(1))) unsigned int*)(aB[i] + kt),
        (__attribute__((address_space(3))) unsigned int*)&As[(i*256 + w*64)*8], 16, 0, 0);
      __builtin_amdgcn_global_load_lds(
        (const __attribute__((address_space(1))) unsigned int*)(bB[i] + kt),
        (__attribute__((address_space(3))) unsigned int*)&Bs[(i*256 + w*64)*8], 16, 0, 0);
    }
    __syncthreads();
    #pragma unroll
    for (int ks = 0; ks < 2; ++ks){
      bf16x8 aF[4], bF[4];
      #pragma unroll
      for (int mi = 0; mi < 4; ++mi)
        aF[mi] = *(const bf16x8*)(&As[(wr*64 + mi*16 + (l & 15))*64 + ks*32 + (l >> 4)*8]);
      #pragma unroll
      for (int ni = 0; ni < 4; ++ni)
        bF[ni] = *(const bf16x8*)(&Bs[(wc*64 + ni*16 + (l & 15))*64 + ks*32 + (l >> 4)*8]);
      #pragma unroll
      for (int mi = 0; mi < 4; ++mi)
        #pragma unroll
        for (int ni = 0; ni < 4; ++ni)
          acc[mi][ni] = __builtin_amdgcn_mfma_f32_16x16x32_bf16(aF[mi], bF[ni], acc[mi][ni], 0, 0, 0);
    }
    __syncthreads();
  }
  // D layout: col = lane&15, row = (lane>>4)*4 + j  (m89-verified)
  #pragma unroll
  for (int mi = 0; mi < 4; ++mi){
    #pragma unroll
    for (int ni = 0; ni < 4; ++ni){
      int col = bn + wc*64 + ni*16 + (l & 15);
      int row0 = bm + wr*64 + mi*16 + ((l >> 4) << 2);
      #pragma unroll
      for (int j = 0; j < 4; ++j){
        int row = row0 + j;
        float v = acc[mi][ni][j] * scale;
        if (bias) v += bias[col];
        if constexpr (EPI == 3) v += pe[((row & 63) << 9) + col];
        if constexpr (EPI == 0){
          Cf[cOff + (long)row*ldc + col] = v;
        } else if constexpr (EPI == 4){
          long orow = (long)(row & 63)*512 + (row >> 6);
          Cf[orow*ldc + col] = v;
        } else {
          Cb[cOff + (long)row*ldc + col] = f2bf(v);
        }
      }
    }
  }
}

// ---------------- epilogues / glue ----------------
__global__ __launch_bounds__(256) void ucepi_kernel(const unsigned short* __restrict__ uc,
                                                    float* __restrict__ outp){
  int id = blockIdx.x*256 + threadIdx.x;   // 32768*128
  int m = id >> 7, n = id & 127;
  float ul = b2f(uc[(long)m*256 + n]);
  float cl = b2f(uc[(long)m*256 + 128 + n]);
  float u = 1.f / (1.f + expf(-ul));
  outp[id] = (1.f - u) * tanhf(cl);
}

// Afus[(n*64+b)][c] = fusion[b,c,n] = concat([hs,hl])[b*512 + 2c + (n>>8), n&255]
__global__ __launch_bounds__(256) void afus_kernel(const float* __restrict__ out,
                                                   unsigned short* __restrict__ Afus){
  int rc = blockIdx.x, a = blockIdx.y, b = blockIdx.z;
  int c = threadIdx.x;  // 0..255
  const float* hsrc = out + 2*OUTSEC;   // hs
  const float* hlrc = out + 1*OUTSEC;   // hl
  long rowb = (long)b*512 + 2*c + a;
  #pragma unroll 4
  for (int r0 = 0; r0 < 32; ++r0){
    int r = rc*32 + r0;
    float v = (r < 128) ? hsrc[rowb*128 + r] : hlrc[rowb*128 + (r - 128)];
    long mrow = (long)(a*256 + r)*64 + b;
    Afus[mrow*256 + c] = f2bf(v);
  }
}

// vT[g=(b,h)][d][t] = qkv[t*64+b][1024 + h*256 + d]  (64x64 LDS transpose tiles)
__global__ __launch_bounds__(256) void vt_kernel(const unsigned short* __restrict__ qkv,
                                                 unsigned short* __restrict__ vT){
  int g = blockIdx.y; int b = g >> 1, h = g & 1;
  int tt = blockIdx.x & 7, dt = blockIdx.x >> 3;
  __shared__ unsigned short sm[64][65];
  int lrow = threadIdx.x >> 6, lcol = threadIdx.x & 63;
  const unsigned short* src = qkv + (long)b*1536 + 1024 + (long)h*256 + dt*64;
  #pragma unroll
  for (int i = 0; i < 16; ++i){
    int t = tt*64 + lrow + i*4;
    sm[lrow + i*4][lcol] = src[(long)t*98304 + lcol];
  }
  __syncthreads();
  unsigned short* dstp = vT + (long)g*131072 + (long)(dt*64)*512 + tt*64;
  #pragma unroll
  for (int i = 0; i < 16; ++i){
    int d = lrow + i*4;
    dstp[(long)d*512 + lcol] = sm[lcol][d];
  }
}

__global__ __launch_bounds__(256) void softmax_kernel(const float* __restrict__ S,
                                                      unsigned short* __restrict__ P){
  int row = blockIdx.x*4 + (threadIdx.x >> 6);
  int l = threadIdx.x & 63;
  const fvec4* sr = (const fvec4*)(S + (long)row*512);
  fvec4 v0 = sr[l], v1 = sr[l + 64];
  float m = fmaxf(fmaxf(fmaxf(v0[0],v0[1]), fmaxf(v0[2],v0[3])),
                  fmaxf(fmaxf(v1[0],v1[1]), fmaxf(v1[2],v1[3])));
  #pragma unroll
  for (int off = 32; off; off >>= 1) m = fmaxf(m, __shfl_xor(m, off));
  float e0[4], e1[4], s = 0.f;
  #pragma unroll
  for (int j = 0; j < 4; ++j){ e0[j] = expf(v0[j]-m); s += e0[j]; }
  #pragma unroll
  for (int j = 0; j < 4; ++j){ e1[j] = expf(v1[j]-m); s += e1[j]; }
  #pragma unroll
  for (int off = 32; off; off >>= 1) s += __shfl_xor(s, off);
  float inv = 1.f / s;
  u16x4 p0 = { f2bf(e0[0]*inv), f2bf(e0[1]*inv), f2bf(e0[2]*inv), f2bf(e0[3]*inv) };
  u16x4 p1 = { f2bf(e1[0]*inv), f2bf(e1[1]*inv), f2bf(e1[2]*inv), f2bf(e1[3]*inv) };
  *(u16x4*)(P + (long)row*512 + l*4) = p0;
  *(u16x4*)(P + (long)row*512 + 256 + l*4) = p1;
}

// ---------------- host ----------------
extern "C" void kernel_launch(void* const* d_in, const int* in_sizes, int n_in,
                              void* d_out, int out_size, void* d_ws, size_t ws_size,
                              hipStream_t stream)
{
  (void)in_sizes; (void)n_in; (void)out_size;
  constexpr long MB = 1l << 20;
  if (ws_size < 216*MB) return;  // layout needs 216 MiB; fail loudly via absmax

  const float* xin[3] = {(const float*)d_in[0], (const float*)d_in[1], (const float*)d_in[2]};
  const int*   ei = (const int*)d_in[3];
  const float* ew = (const float*)d_in[4];
  const float* Wru[3] = {(const float*)d_in[5], (const float*)d_in[9],  (const float*)d_in[13]};
  const float* bru[3] = {(const float*)d_in[6], (const float*)d_in[10], (const float*)d_in[14]};
  const float* Wc[3]  = {(const float*)d_in[7], (const float*)d_in[11], (const float*)d_in[15]};
  const float* bc[3]  = {(const float*)d_in[8], (const float*)d_in[12], (const float*)d_in[16]};
  const float* Whd  = (const float*)d_in[17]; const float* bhd   = (const float*)d_in[18];
  const float* Win  = (const float*)d_in[19]; const float* bin   = (const float*)d_in[20];
  const float* Wout = (const float*)d_in[21]; const float* bout  = (const float*)d_in[22];
  const float* Wgt  = (const float*)d_in[23]; const float* bgate = (const float*)d_in[24];
  float* out = (float*)d_out;
  char* ws = (char*)d_ws;

  float*    deg    = (float*)(ws + 0);
  unsigned* cnt    = (unsigned*)(ws + 131072);
  unsigned* rowptr = (unsigned*)(ws + 262144);
  unsigned* curs   = (unsigned*)(ws + 524288);
  unsigned* csrc   = (unsigned*)(ws + 786432);
  float*    csrw   = (float*)(ws + 1835008);
  unsigned short* Weff = (unsigned short*)(ws + 2883584);   // 3 x [256][768]
  float*    beff   = (float*)(ws + 4063232);                // 3 x 256
  unsigned short* WHD   = (unsigned short*)(ws + 4194304);  // [512][256]
  unsigned short* WIN   = (unsigned short*)(ws + 4456448);  // [1536][512]
  unsigned short* WOUTB = (unsigned short*)(ws + 6029312);  // [512][512]
  unsigned short* WGTB  = (unsigned short*)(ws + 6553600);  // [128][512]
  float*    PE     = (float*)(ws + 6684672);                // [64][512]
  unsigned short* XATT = (unsigned short*)(ws + 8*MB);      // [32768][512] (dies after qkv)
  unsigned short* ZCAT = (unsigned short*)(ws + 40*MB);     // [32768][768] (phase A)
  unsigned short* UC   = (unsigned short*)(ws + 88*MB);     // [32768][256] (phase A)
  unsigned short* AFUS = (unsigned short*)(ws + 40*MB);     // [32768][256] (phase B)
  unsigned short* QKV  = (unsigned short*)(ws + 40*MB);     // [32768][1536] (phase C+)
  unsigned short* VT   = (unsigned short*)(ws + 136*MB);    // [128][256][512]
  unsigned short* CTX  = (unsigned short*)(ws + 168*MB);    // [32768][512]
  float*    SCORES = (float*)(ws + 8*MB);                   // [32][512][512] (reuses XATT)
  unsigned short* PBUF = (unsigned short*)(ws + 200*MB);    // [32][512][512] bf16
  unsigned short* ATTO = (unsigned short*)(ws + 8*MB);      // [32768][512] (reuses SCORES)

  // graph build
  hipMemsetAsync(deg,  0, 131072, stream);
  hipMemsetAsync(cnt,  0, 131072, stream);
  hipMemsetAsync(curs, 0, 131072, stream);
  histdeg_kernel<<<1024, 256, 0, stream>>>(ei, ew, cnt, deg);
  scan_kernel<<<1, 1024, 0, stream>>>(cnt, rowptr);
  scatter_kernel<<<1024, 256, 0, stream>>>(ei, ew, rowptr, curs, csrc, csrw);

  // weight prep
  for (int br = 0; br < 3; ++br)
    weff_kernel<<<768, 256, 0, stream>>>(Wru[br], bru[br], Wc[br], bc[br],
                                         Weff + (long)br*196608, beff + br*256);
  cvt_f2b_kernel<<<512,  256, 0, stream>>>(Whd,  WHD,   131072);
  cvt_f2b_kernel<<<3072, 256, 0, stream>>>(Win,  WIN,   786432);
  cvt_f2b_kernel<<<1024, 256, 0, stream>>>(Wout, WOUTB, 262144);
  cvt_f2b_kernel<<<256,  256, 0, stream>>>(Wgt,  WGTB,  65536);
  pe_kernel<<<128, 256, 0, stream>>>(PE);

  // branches: hf (x_od), hl (history), hs (yesterday) -> out sections 0,1,2
  for (int br = 0; br < 3; ++br){
    convx_kernel<<<8192, 256, 0, stream>>>(xin[br], ZCAT);
    prop_kernel<0><<<8192, 256, 0, stream>>>(xin[br], nullptr, ZCAT + 256,
                                             rowptr, csrc, csrw, deg);
    prop_kernel<1><<<8192, 256, 0, stream>>>(nullptr, ZCAT + 256, ZCAT + 512,
                                             rowptr, csrc, csrw, deg);
    gemm_bt<0,2><<<dim3(2,256,1), 256, 0, stream>>>(ZCAT, Weff + (long)br*196608,
        nullptr, UC, 768, 768, 768, 256, 0,0,0, 0, beff + br*256, nullptr, 1.0f);
    ucepi_kernel<<<16384, 256, 0, stream>>>(UC, out + (long)br*OUTSEC);
  }

  // fusion gather + uh GEMM (bias + pos-enc fused) -> x_att bf16
  afus_kernel<<<dim3(8,2,64), 256, 0, stream>>>(out, AFUS);
  gemm_bt<0,3><<<dim3(4,256,1), 256, 0, stream>>>(AFUS, WHD, nullptr, XATT,
      256, 256, 256, 512, 0,0,0, 0, bhd, PE, 1.0f);

  // qkv
  gemm_bt<0,2><<<dim3(12,256,1), 256, 0, stream>>>(XATT, WIN, nullptr, QKV,
      512, 512, 512, 1536, 0,0,0, 0, bin, nullptr, 1.0f);
  vt_kernel<<<dim3(32,128), 256, 0, stream>>>(QKV, VT);

  // attention in 4 chunks of 32 (b,h) pairs
  for (int c4 = 0; c4 < 4; ++c4){
    gemm_bt<1,0><<<dim3(4,4,32), 256, 0, stream>>>(QKV, QKV, SCORES, nullptr,
        256, 98304, 98304, 512, 0,0,0, c4*32, nullptr, nullptr, 0.0625f);
    softmax_kernel<<<4096, 256, 0, stream>>>(SCORES, PBUF);
    gemm_bt<2,2><<<dim3(2,4,32), 256, 0, stream>>>(PBUF, VT, nullptr, CTX,
        512, 512, 512, 32768, 0,0,0, c4*32, nullptr, nullptr, 1.0f);
  }

  // attn_out and gated output (row remap (n,b) -> b*512+n fused into epilogue)
  gemm_bt<0,2><<<dim3(4,256,1), 256, 0, stream>>>(CTX, WOUTB, nullptr, ATTO,
      512, 512, 512, 512, 0,0,0, 0, bout, nullptr, 1.0f);
  gemm_bt<0,4><<<dim3(1,256,1), 256, 0, stream>>>(ATTO, WGTB, out + 3*OUTSEC, nullptr,
      512, 512, 512, 128, 0,0,0, 0, bgate, nullptr, 1.0f);
}

// Round 5
// 1042.059 us; speedup vs baseline: 1.0618x; 1.0499x over previous
//
#include <hip/hip_runtime.h>
#include <hip/hip_bf16.h>
#include <math.h>

// ODNet_att: 3×(graph-GRU with h0=0) + hidden-fusion + 2-head self-attention.
// R5: algebraic GEMM fusion. uh+qkv collapsed (qkv = AFUS @ (Win*Whd) + peq[b],
// K=256) and wout+wgate collapsed (out = ctx @ (Wout^T*Wgate^T) + beq).
// Fused weights precomputed on-device per call. gemm_bt keeps global_load_lds
// width=16 staging (R4).

#define DEV __device__ __forceinline__

typedef __attribute__((ext_vector_type(4))) float  f32x4;
typedef __attribute__((ext_vector_type(4))) float  fvec4;
typedef __attribute__((ext_vector_type(8))) short  bf16x8;
typedef __attribute__((ext_vector_type(4))) unsigned short u16x4;

constexpr int BN_ = 32768;     // B*N = 64*512
constexpr int E_  = 262144;    // edges
constexpr long OUTSEC = 4194304; // 32768*128 per output section

DEV unsigned short f2bf(float f){
  union { float f; unsigned u; } v; v.f = f;
  unsigned r = (v.u + 0x7FFFu + ((v.u >> 16) & 1u)) >> 16;
  return (unsigned short)r;
}
DEV float b2f(unsigned short h){
  union { unsigned u; float f; } v; v.u = ((unsigned)h) << 16;
  return v.f;
}

// ---------------- graph build ----------------
__global__ __launch_bounds__(256) void histdeg_kernel(const int* __restrict__ ei,
    const float* __restrict__ ew, unsigned* __restrict__ cnt, float* __restrict__ deg){
  int e = blockIdx.x*256 + threadIdx.x;
  int d = ei[E_ + e];
  atomicAdd(&cnt[d], 1u);
  atomicAdd(&deg[d], ew[e]);
}

__global__ __launch_bounds__(1024) void scan_kernel(const unsigned* __restrict__ cnt,
                                                    unsigned* __restrict__ rowptr){
  __shared__ unsigned sm[1024];
  __shared__ unsigned carry;
  int tid = threadIdx.x;
  if (tid == 0) carry = 0;
  __syncthreads();
  for (int base = 0; base < BN_; base += 1024){
    unsigned v = cnt[base + tid];
    sm[tid] = v;
    __syncthreads();
    for (int off = 1; off < 1024; off <<= 1){
      unsigned t = (tid >= off) ? sm[tid - off] : 0u;
      __syncthreads();
      sm[tid] += t;
      __syncthreads();
    }
    rowptr[base + tid] = carry + sm[tid] - v;  // exclusive prefix
    __syncthreads();
    if (tid == 1023) carry += sm[1023];
    __syncthreads();
  }
  if (tid == 0) rowptr[BN_] = carry;
}

__global__ __launch_bounds__(256) void scatter_kernel(const int* __restrict__ ei,
    const float* __restrict__ ew, const unsigned* __restrict__ rowptr,
    unsigned* __restrict__ curs, unsigned* __restrict__ csrc, float* __restrict__ csrw){
  int e = blockIdx.x*256 + threadIdx.x;
  int d = ei[E_ + e];
  unsigned pos = atomicAdd(&curs[d], 1u);
  unsigned idx = rowptr[d] + pos;
  csrc[idx] = (unsigned)ei[e];
  csrw[idx] = ew[e];
}

// ---------------- propagation: one wave per node, 4 feats/lane ----------------
template<int SRC>  // 0: read f32 input, 1: read bf16 from zcat (pre-offset ptr)
__global__ __launch_bounds__(256) void prop_kernel(const float* __restrict__ xf,
    const unsigned short* __restrict__ zin, unsigned short* __restrict__ zout,
    const unsigned* __restrict__ rowptr, const unsigned* __restrict__ csrc,
    const float* __restrict__ csrw, const float* __restrict__ deg){
  int node = blockIdx.x*4 + (threadIdx.x >> 6);
  int l = threadIdx.x & 63;
  unsigned b0 = rowptr[node], b1 = rowptr[node + 1];
  float a0 = 0.f, a1 = 0.f, a2 = 0.f, a3 = 0.f;
  for (unsigned e = b0; e < b1; ++e){
    int s = csrc[e]; float w = csrw[e];
    if constexpr (SRC == 0){
      fvec4 v = *(const fvec4*)(xf + (long)s*256 + l*4);
      a0 += w*v[0]; a1 += w*v[1]; a2 += w*v[2]; a3 += w*v[3];
    } else {
      u16x4 v = *(const u16x4*)(zin + (long)s*768 + l*4);
      a0 += w*b2f(v[0]); a1 += w*b2f(v[1]); a2 += w*b2f(v[2]); a3 += w*b2f(v[3]);
    }
  }
  float dg = deg[node]; dg = dg > 1.f ? dg : 1.f;
  float inv = 1.f / dg;
  u16x4 o = { f2bf(a0*inv), f2bf(a1*inv), f2bf(a2*inv), f2bf(a3*inv) };
  *(u16x4*)(zout + (long)node*768 + l*4) = o;
}

// x (f32 [BN][256]) -> zcat cols 0:256 (bf16, row stride 768)
__global__ __launch_bounds__(256) void convx_kernel(const float* __restrict__ xf,
                                                    unsigned short* __restrict__ zcat){
  int id = blockIdx.x*256 + threadIdx.x;   // over 32768*64
  fvec4 v = ((const fvec4*)xf)[id];
  int m = id >> 6, c4 = id & 63;
  u16x4 o = { f2bf(v[0]), f2bf(v[1]), f2bf(v[2]), f2bf(v[3]) };
  *(u16x4*)(zcat + (long)m*768 + c4*4) = o;
}

// ---------------- weight prep ----------------
__global__ __launch_bounds__(256) void cvt_f2b_kernel(const float* __restrict__ s,
                                                      unsigned short* __restrict__ d, int n){
  int i = blockIdx.x*256 + threadIdx.x;
  if (i < n) d[i] = f2bf(s[i]);
}

// transpose+convert: src f32 [R][2^lgC] -> dst bf16 [2^lgC][R]
__global__ __launch_bounds__(256) void tcvt_kernel(const float* __restrict__ s,
    unsigned short* __restrict__ d, int lgC, int R){
  int id = blockIdx.x*256 + threadIdx.x;
  int r = id >> lgC, c = id & ((1 << lgC) - 1);
  d[(long)c*R + r] = f2bf(s[id]);
}

// Build BT[256][768]: cols 0:128 = u-part of W_ru (cols 128:256), 128:256 = W_c.
// k -> W row (k>>8)*384 + (k&255)  (only x-rows of each hop block matter; h==0).
__global__ __launch_bounds__(256) void weff_kernel(const float* __restrict__ Wru,
    const float* __restrict__ bru, const float* __restrict__ Wc, const float* __restrict__ bc,
    unsigned short* __restrict__ Weff, float* __restrict__ beff){
  int id = blockIdx.x*256 + threadIdx.x;   // 256*768
  int n = id / 768, k = id % 768;
  int row = (k >> 8)*384 + (k & 255);
  float w = (n < 128) ? Wru[(long)row*256 + 128 + n] : Wc[(long)row*128 + (n - 128)];
  Weff[(long)n*768 + k] = f2bf(w);
  if (k == 0) beff[n] = (n < 128) ? bru[128 + n] : bc[n - 128];
}

// PET4[(o>>2)*256 + b*4 + (o&3)] = pos_enc(b,o) + bhd[o]   (f32, [64]x[512] folded)
__global__ __launch_bounds__(256) void pe_kernel(const float* __restrict__ bhd,
                                                 float* __restrict__ PET4){
  int id = blockIdx.x*256 + threadIdx.x;   // 64*512
  int b = id >> 9, o = id & 511;
  float j2 = (float)(o & ~1);
  float ang = (float)b * expf(-j2 * (9.210340371976184f / 512.f)); // ln(1e4)
  float v = ((o & 1) ? cosf(ang) : sinf(ang)) + bhd[o];
  PET4[(o >> 2)*256 + b*4 + (o & 3)] = v;
}

// peq2[b][j] = bin[j] + sum_o PET(b,o) * Win[j][o]   (wave per j, lane = b)
__global__ __launch_bounds__(256) void peq2_kernel(const float* __restrict__ Win,
    const float* __restrict__ bin, const float* __restrict__ PET4, float* __restrict__ peq2){
  int j = blockIdx.x*4 + (threadIdx.x >> 6);
  int l = threadIdx.x & 63;
  float acc = 0.f;
  for (int o4 = 0; o4 < 128; ++o4){
    fvec4 wv = *(const fvec4*)(Win + (long)j*512 + o4*4);   // broadcast across lanes
    fvec4 pv = *(const fvec4*)(PET4 + o4*256 + l*4);        // coalesced
    acc += wv[0]*pv[0] + wv[1]*pv[1] + wv[2]*pv[2] + wv[3]*pv[3];
  }
  peq2[(long)l*1536 + j] = bin[j] + acc;
}

// beq[g] = bgate[g] + dot(Wgate[g,:], bout)
__global__ __launch_bounds__(128) void beq_kernel(const float* __restrict__ Wgt,
    const float* __restrict__ bout, const float* __restrict__ bgate, float* __restrict__ beq){
  int g = threadIdx.x;
  float s = bgate[g];
  for (int c = 0; c < 512; ++c) s += Wgt[(long)g*512 + c] * bout[c];
  beq[g] = s;
}

// ---------------- shared bf16 MFMA GEMM ----------------
// C[m][n] = scale * sum_k A[m][k]*Bt[n][k] (+bias[n]) (+pe)  ; tiles 128x128, BK=64.
// Staging: global_load_lds width=16 (linear LDS dest = lane order).
// MODE 0: plain. MODE 1: attn scores (A=Q,Bt=K from qkv). MODE 2: ctx (P@V^T).
// EPI 0: f32 store. 2: bf16 store. 4: f32 + row remap (n,b)->(b*512+n).
// EPI 5: bf16 store + per-(row&63) f32 row-table add (fused pe/bias for qkv).
template<int MODE, int EPI>
__global__ __launch_bounds__(256) void gemm_bt(
    const unsigned short* __restrict__ A, const unsigned short* __restrict__ Bt,
    float* __restrict__ Cf, unsigned short* __restrict__ Cb,
    int Ktot, int lda, int ldb, int ldc,
    long sA, long sB, long sC, int g0,
    const float* __restrict__ bias, const float* __restrict__ pe, float scale)
{
  __shared__ unsigned short As[128*64];
  __shared__ unsigned short Bs[128*64];
  const int tid = threadIdx.x;
  long aOff, bOff, cOff;
  if constexpr (MODE == 0){
    aOff = blockIdx.z * sA; bOff = blockIdx.z * sB; cOff = blockIdx.z * sC;
  } else if constexpr (MODE == 1){
    int g = g0 + blockIdx.z;
    long base = (long)(g >> 1)*1536 + (long)(g & 1)*256;
    aOff = base; bOff = base + 512; cOff = (long)blockIdx.z * 262144;
  } else {
    int g = g0 + blockIdx.z;
    aOff = (long)blockIdx.z * 262144;
    bOff = (long)g * 131072;
    cOff = (long)g * 256;
  }
  const int bm = blockIdx.y * 128, bn = blockIdx.x * 128;
  const int w = tid >> 6, l = tid & 63;
  const int wr = w >> 1, wc = w & 1;

  // per-lane global staging bases (element offsets); LDS dest is linear in c
  const unsigned short* aB[4];
  const unsigned short* bB[4];
  #pragma unroll
  for (int i = 0; i < 4; ++i){
    int c = tid + i*256;
    int row = c >> 3, gg = c & 7;
    aB[i] = A  + aOff + (long)(bm + row)*lda + gg*8;
    bB[i] = Bt + bOff + (long)(bn + row)*ldb + gg*8;
  }

  f32x4 acc[4][4] = {};
  for (int kt = 0; kt < Ktot; kt += 64){
    #pragma unroll
    for (int i = 0; i < 4; ++i){
      __builtin_amdgcn_global_load_lds(
        (const __attribute__((address_space(1))) unsigned int*)(aB[i] + kt),
        (__attribute__((address_space(3))) unsigned int*)&As[(i*256 + w*64)*8], 16, 0, 0);
      __builtin_amdgcn_global_load_lds(
        (const __attribute__((address_space(1))) unsigned int*)(bB[i] + kt),
        (__attribute__((address_space(3))) unsigned int*)&Bs[(i*256 + w*64)*8], 16, 0, 0);
    }
    __syncthreads();
    #pragma unroll
    for (int ks = 0; ks < 2; ++ks){
      bf16x8 aF[4], bF[4];
      #pragma unroll
      for (int mi = 0; mi < 4; ++mi)
        aF[mi] = *(const bf16x8*)(&As[(wr*64 + mi*16 + (l & 15))*64 + ks*32 + (l >> 4)*8]);
      #pragma unroll
      for (int ni = 0; ni < 4; ++ni)
        bF[ni] = *(const bf16x8*)(&Bs[(wc*64 + ni*16 + (l & 15))*64 + ks*32 + (l >> 4)*8]);
      #pragma unroll
      for (int mi = 0; mi < 4; ++mi)
        #pragma unroll
        for (int ni = 0; ni < 4; ++ni)
          acc[mi][ni] = __builtin_amdgcn_mfma_f32_16x16x32_bf16(aF[mi], bF[ni], acc[mi][ni], 0, 0, 0);
    }
    __syncthreads();
  }
  // D layout: col = lane&15, row = (lane>>4)*4 + j  (m89-verified)
  #pragma unroll
  for (int mi = 0; mi < 4; ++mi){
    #pragma unroll
    for (int ni = 0; ni < 4; ++ni){
      int col = bn + wc*64 + ni*16 + (l & 15);
      int row0 = bm + wr*64 + mi*16 + ((l >> 4) << 2);
      #pragma unroll
      for (int j = 0; j < 4; ++j){
        int row = row0 + j;
        float v = acc[mi][ni][j] * scale;
        if (bias) v += bias[col];
        if constexpr (EPI == 5) v += pe[((row & 63) * 1536) + col];
        if constexpr (EPI == 0){
          Cf[cOff + (long)row*ldc + col] = v;
        } else if constexpr (EPI == 4){
          long orow = (long)(row & 63)*512 + (row >> 6);
          Cf[orow*ldc + col] = v;
        } else {
          Cb[cOff + (long)row*ldc + col] = f2bf(v);
        }
      }
    }
  }
}

// ---------------- epilogues / glue ----------------
__global__ __launch_bounds__(256) void ucepi_kernel(const unsigned short* __restrict__ uc,
                                                    float* __restrict__ outp){
  int id = blockIdx.x*256 + threadIdx.x;   // 32768*128
  int m = id >> 7, n = id & 127;
  float ul = b2f(uc[(long)m*256 + n]);
  float cl = b2f(uc[(long)m*256 + 128 + n]);
  float u = 1.f / (1.f + expf(-ul));
  outp[id] = (1.f - u) * tanhf(cl);
}

// Afus[(n*64+b)][c] = fusion[b,c,n] = concat([hs,hl])[b*512 + 2c + (n>>8), n&255]
__global__ __launch_bounds__(256) void afus_kernel(const float* __restrict__ out,
                                                   unsigned short* __restrict__ Afus){
  int rc = blockIdx.x, a = blockIdx.y, b = blockIdx.z;
  int c = threadIdx.x;  // 0..255
  const float* hsrc = out + 2*OUTSEC;   // hs
  const float* hlrc = out + 1*OUTSEC;   // hl
  long rowb = (long)b*512 + 2*c + a;
  #pragma unroll 4
  for (int r0 = 0; r0 < 32; ++r0){
    int r = rc*32 + r0;
    float v = (r < 128) ? hsrc[rowb*128 + r] : hlrc[rowb*128 + (r - 128)];
    long mrow = (long)(a*256 + r)*64 + b;
    Afus[mrow*256 + c] = f2bf(v);
  }
}

// vT[g=(b,h)][d][t] = qkv[t*64+b][1024 + h*256 + d]  (64x64 LDS transpose tiles)
__global__ __launch_bounds__(256) void vt_kernel(const unsigned short* __restrict__ qkv,
                                                 unsigned short* __restrict__ vT){
  int g = blockIdx.y; int b = g >> 1, h = g & 1;
  int tt = blockIdx.x & 7, dt = blockIdx.x >> 3;
  __shared__ unsigned short sm[64][65];
  int lrow = threadIdx.x >> 6, lcol = threadIdx.x & 63;
  const unsigned short* src = qkv + (long)b*1536 + 1024 + (long)h*256 + dt*64;
  #pragma unroll
  for (int i = 0; i < 16; ++i){
    int t = tt*64 + lrow + i*4;
    sm[lrow + i*4][lcol] = src[(long)t*98304 + lcol];
  }
  __syncthreads();
  unsigned short* dstp = vT + (long)g*131072 + (long)(dt*64)*512 + tt*64;
  #pragma unroll
  for (int i = 0; i < 16; ++i){
    int d = lrow + i*4;
    dstp[(long)d*512 + lcol] = sm[lcol][d];
  }
}

__global__ __launch_bounds__(256) void softmax_kernel(const float* __restrict__ S,
                                                      unsigned short* __restrict__ P){
  int row = blockIdx.x*4 + (threadIdx.x >> 6);
  int l = threadIdx.x & 63;
  const fvec4* sr = (const fvec4*)(S + (long)row*512);
  fvec4 v0 = sr[l], v1 = sr[l + 64];
  float m = fmaxf(fmaxf(fmaxf(v0[0],v0[1]), fmaxf(v0[2],v0[3])),
                  fmaxf(fmaxf(v1[0],v1[1]), fmaxf(v1[2],v1[3])));
  #pragma unroll
  for (int off = 32; off; off >>= 1) m = fmaxf(m, __shfl_xor(m, off));
  float e0[4], e1[4], s = 0.f;
  #pragma unroll
  for (int j = 0; j < 4; ++j){ e0[j] = expf(v0[j]-m); s += e0[j]; }
  #pragma unroll
  for (int j = 0; j < 4; ++j){ e1[j] = expf(v1[j]-m); s += e1[j]; }
  #pragma unroll
  for (int off = 32; off; off >>= 1) s += __shfl_xor(s, off);
  float inv = 1.f / s;
  u16x4 p0 = { f2bf(e0[0]*inv), f2bf(e0[1]*inv), f2bf(e0[2]*inv), f2bf(e0[3]*inv) };
  u16x4 p1 = { f2bf(e1[0]*inv), f2bf(e1[1]*inv), f2bf(e1[2]*inv), f2bf(e1[3]*inv) };
  *(u16x4*)(P + (long)row*512 + l*4) = p0;
  *(u16x4*)(P + (long)row*512 + 256 + l*4) = p1;
}

// ---------------- host ----------------
extern "C" void kernel_launch(void* const* d_in, const int* in_sizes, int n_in,
                              void* d_out, int out_size, void* d_ws, size_t ws_size,
                              hipStream_t stream)
{
  (void)in_sizes; (void)n_in; (void)out_size;
  constexpr long MB = 1l << 20;
  if (ws_size < 216*MB) return;  // layout needs 216 MiB; fail loudly via absmax

  const float* xin[3] = {(const float*)d_in[0], (const float*)d_in[1], (const float*)d_in[2]};
  const int*   ei = (const int*)d_in[3];
  const float* ew = (const float*)d_in[4];
  const float* Wru[3] = {(const float*)d_in[5], (const float*)d_in[9],  (const float*)d_in[13]};
  const float* bru[3] = {(const float*)d_in[6], (const float*)d_in[10], (const float*)d_in[14]};
  const float* Wc[3]  = {(const float*)d_in[7], (const float*)d_in[11], (const float*)d_in[15]};
  const float* bc[3]  = {(const float*)d_in[8], (const float*)d_in[12], (const float*)d_in[16]};
  const float* Whd  = (const float*)d_in[17]; const float* bhd   = (const float*)d_in[18];
  const float* Win  = (const float*)d_in[19]; const float* bin   = (const float*)d_in[20];
  const float* Wout = (const float*)d_in[21]; const float* bout  = (const float*)d_in[22];
  const float* Wgt  = (const float*)d_in[23]; const float* bgate = (const float*)d_in[24];
  float* out = (float*)d_out;
  char* ws = (char*)d_ws;

  float*    deg    = (float*)(ws + 0);
  unsigned* cnt    = (unsigned*)(ws + 131072);
  unsigned* rowptr = (unsigned*)(ws + 262144);
  unsigned* curs   = (unsigned*)(ws + 524288);
  unsigned* csrc   = (unsigned*)(ws + 786432);
  float*    csrw   = (float*)(ws + 1835008);
  unsigned short* Weff = (unsigned short*)(ws + 2883584);   // 3 x [256][768]
  float*    beff   = (float*)(ws + 4063232);                // 3 x 256 f32
  float*    beq    = (float*)(ws + 4194304);                // 128 f32
  unsigned short* WIN   = (unsigned short*)(ws + 4456448);  // [1536][512] bf16
  unsigned short* WGTB  = (unsigned short*)(ws + 6029312);  // [128][512] bf16
  unsigned short* WHDT  = (unsigned short*)(ws + 6160384);  // [256][512] bf16 (Whd^T)
  unsigned short* WOUTT = (unsigned short*)(ws + 6422528);  // [512][512] bf16 (Wout^T)
  unsigned short* Wq2t  = (unsigned short*)(ws + 6946816);  // [1536][256] bf16 (Win*Whd)
  unsigned short* Weqt  = (unsigned short*)(ws + 7733248);  // [128][512] bf16 (Wgate*Wout)
  float*    PET4   = (float*)(ws + 7864320);                // [128][64][4] f32 (pe+bhd)^T
  float*    PEQ2   = (float*)(ws + 7995392);                // [64][1536] f32 (ends at 8MB)
  unsigned short* AFUS = (unsigned short*)(ws + 8*MB);      // [32768][256] (dies after qkv)
  unsigned short* ZCAT = (unsigned short*)(ws + 40*MB);     // [32768][768] (phase A)
  unsigned short* UC   = (unsigned short*)(ws + 88*MB);     // [32768][256] (phase A)
  unsigned short* QKV  = (unsigned short*)(ws + 40*MB);     // [32768][1536] (phase C+)
  unsigned short* VT   = (unsigned short*)(ws + 136*MB);    // [128][256][512]
  unsigned short* CTX  = (unsigned short*)(ws + 168*MB);    // [n][b*512+o] flat 32MB
  float*    SCORES = (float*)(ws + 8*MB);                   // [32][512][512] (reuses AFUS)
  unsigned short* PBUF = (unsigned short*)(ws + 200*MB);    // [32][512][512] bf16

  // graph build
  hipMemsetAsync(deg,  0, 131072, stream);
  hipMemsetAsync(cnt,  0, 131072, stream);
  hipMemsetAsync(curs, 0, 131072, stream);
  histdeg_kernel<<<1024, 256, 0, stream>>>(ei, ew, cnt, deg);
  scan_kernel<<<1, 1024, 0, stream>>>(cnt, rowptr);
  scatter_kernel<<<1024, 256, 0, stream>>>(ei, ew, rowptr, curs, csrc, csrw);

  // weight prep
  for (int br = 0; br < 3; ++br)
    weff_kernel<<<768, 256, 0, stream>>>(Wru[br], bru[br], Wc[br], bc[br],
                                         Weff + (long)br*196608, beff + br*256);
  cvt_f2b_kernel<<<3072, 256, 0, stream>>>(Win, WIN,  786432);
  cvt_f2b_kernel<<<256,  256, 0, stream>>>(Wgt, WGTB, 65536);
  tcvt_kernel<<<512,  256, 0, stream>>>(Whd,  WHDT,  8, 512);   // [512][256] -> [256][512]
  tcvt_kernel<<<1024, 256, 0, stream>>>(Wout, WOUTT, 9, 512);   // [512][512] -> [512][512]^T
  pe_kernel<<<128, 256, 0, stream>>>(bhd, PET4);

  // fused-weight precompute:
  // Wq2t[n][k] = sum_o WIN[n][o]*WHDT[k][o]  (qkv weight, K=256)
  gemm_bt<0,2><<<dim3(2,12,1), 256, 0, stream>>>(WIN, WHDT, nullptr, Wq2t,
      512, 512, 512, 256, 0,0,0, 0, nullptr, nullptr, 1.0f);
  // Weqt[g][o] = sum_c WGTB[g][c]*WOUTT[o][c]  (gated-output weight)
  gemm_bt<0,2><<<dim3(4,1,1), 256, 0, stream>>>(WGTB, WOUTT, nullptr, Weqt,
      512, 512, 512, 512, 0,0,0, 0, nullptr, nullptr, 1.0f);
  peq2_kernel<<<384, 256, 0, stream>>>(Win, bin, PET4, PEQ2);
  beq_kernel<<<1, 128, 0, stream>>>(Wgt, bout, bgate, beq);

  // branches: hf (x_od), hl (history), hs (yesterday) -> out sections 0,1,2
  for (int br = 0; br < 3; ++br){
    convx_kernel<<<8192, 256, 0, stream>>>(xin[br], ZCAT);
    prop_kernel<0><<<8192, 256, 0, stream>>>(xin[br], nullptr, ZCAT + 256,
                                             rowptr, csrc, csrw, deg);
    prop_kernel<1><<<8192, 256, 0, stream>>>(nullptr, ZCAT + 256, ZCAT + 512,
                                             rowptr, csrc, csrw, deg);
    gemm_bt<0,2><<<dim3(2,256,1), 256, 0, stream>>>(ZCAT, Weff + (long)br*196608,
        nullptr, UC, 768, 768, 768, 256, 0,0,0, 0, beff + br*256, nullptr, 1.0f);
    ucepi_kernel<<<16384, 256, 0, stream>>>(UC, out + (long)br*OUTSEC);
  }

  // fusion gather, then fused uh+qkv GEMM (K=256, pe/bias row-table in epilogue)
  afus_kernel<<<dim3(8,2,64), 256, 0, stream>>>(out, AFUS);
  gemm_bt<0,5><<<dim3(12,256,1), 256, 0, stream>>>(AFUS, Wq2t, nullptr, QKV,
      256, 256, 256, 1536, 0,0,0, 0, nullptr, PEQ2, 1.0f);
  vt_kernel<<<dim3(32,128), 256, 0, stream>>>(QKV, VT);

  // attention in 4 chunks of 32 (b,h) pairs
  for (int c4 = 0; c4 < 4; ++c4){
    gemm_bt<1,0><<<dim3(4,4,32), 256, 0, stream>>>(QKV, QKV, SCORES, nullptr,
        256, 98304, 98304, 512, 0,0,0, c4*32, nullptr, nullptr, 0.0625f);
    softmax_kernel<<<4096, 256, 0, stream>>>(SCORES, PBUF);
    gemm_bt<2,2><<<dim3(2,4,32), 256, 0, stream>>>(PBUF, VT, nullptr, CTX,
        512, 512, 512, 32768, 0,0,0, c4*32, nullptr, nullptr, 1.0f);
  }

  // fused wout+wgate output GEMM (row remap (n,b) -> b*512+n in epilogue)
  gemm_bt<0,4><<<dim3(1,256,1), 256, 0, stream>>>(CTX, Weqt, out + 3*OUTSEC, nullptr,
      512, 512, 512, 128, 0,0,0, 0, beq, nullptr, 1.0f);
}

// Round 6
// 993.151 us; speedup vs baseline: 1.1141x; 1.0492x over previous
//
#include <hip/hip_runtime.h>
#include <hip/hip_bf16.h>
#include <math.h>

// ODNet_att R6: batching + epilogue fusion.
//  - branch GEMM fuses (1-sigmoid(u))*tanh(c) via interleaved u/c weight cols
//    + shfl_xor(1) pairing (UC buffer and ucepi deleted).
//  - 3 branches batched over blockIdx.z (convx/prop/gemm), MODE 3.
//  - attention de-chunked: bf16 scores (z=128 single shot), in-place softmax,
//    ctx z=128. gemm_bt keeps global_load_lds width=16 staging.

#define DEV __device__ __forceinline__

typedef __attribute__((ext_vector_type(4))) float  f32x4;
typedef __attribute__((ext_vector_type(4))) float  fvec4;
typedef __attribute__((ext_vector_type(8))) short  bf16x8;
typedef __attribute__((ext_vector_type(4))) unsigned short u16x4;

constexpr int BN_ = 32768;     // B*N = 64*512
constexpr int E_  = 262144;    // edges
constexpr long OUTSEC = 4194304; // 32768*128 per output section
constexpr long ZSZE = 25165824; // 32768*768 elements per branch ZCAT

DEV unsigned short f2bf(float f){
  union { float f; unsigned u; } v; v.f = f;
  unsigned r = (v.u + 0x7FFFu + ((v.u >> 16) & 1u)) >> 16;
  return (unsigned short)r;
}
DEV float b2f(unsigned short h){
  union { unsigned u; float f; } v; v.u = ((unsigned)h) << 16;
  return v.f;
}

// ---------------- graph build ----------------
__global__ __launch_bounds__(256) void histdeg_kernel(const int* __restrict__ ei,
    const float* __restrict__ ew, unsigned* __restrict__ cnt, float* __restrict__ deg){
  int e = blockIdx.x*256 + threadIdx.x;
  int d = ei[E_ + e];
  atomicAdd(&cnt[d], 1u);
  atomicAdd(&deg[d], ew[e]);
}

__global__ __launch_bounds__(1024) void scan_kernel(const unsigned* __restrict__ cnt,
                                                    unsigned* __restrict__ rowptr){
  __shared__ unsigned sm[1024];
  __shared__ unsigned carry;
  int tid = threadIdx.x;
  if (tid == 0) carry = 0;
  __syncthreads();
  for (int base = 0; base < BN_; base += 1024){
    unsigned v = cnt[base + tid];
    sm[tid] = v;
    __syncthreads();
    for (int off = 1; off < 1024; off <<= 1){
      unsigned t = (tid >= off) ? sm[tid - off] : 0u;
      __syncthreads();
      sm[tid] += t;
      __syncthreads();
    }
    rowptr[base + tid] = carry + sm[tid] - v;  // exclusive prefix
    __syncthreads();
    if (tid == 1023) carry += sm[1023];
    __syncthreads();
  }
  if (tid == 0) rowptr[BN_] = carry;
}

__global__ __launch_bounds__(256) void scatter_kernel(const int* __restrict__ ei,
    const float* __restrict__ ew, const unsigned* __restrict__ rowptr,
    unsigned* __restrict__ curs, unsigned* __restrict__ csrc, float* __restrict__ csrw){
  int e = blockIdx.x*256 + threadIdx.x;
  int d = ei[E_ + e];
  unsigned pos = atomicAdd(&curs[d], 1u);
  unsigned idx = rowptr[d] + pos;
  csrc[idx] = (unsigned)ei[e];
  csrw[idx] = ew[e];
}

// ---------------- propagation (z-batched over 3 branches) ----------------
template<int SRC>  // 0: read f32 input (per-z), 1: read bf16 from zcat
__global__ __launch_bounds__(256) void prop3_kernel(const float* __restrict__ x0,
    const float* __restrict__ x1, const float* __restrict__ x2,
    unsigned short* __restrict__ zcat,
    const unsigned* __restrict__ rowptr, const unsigned* __restrict__ csrc,
    const float* __restrict__ csrw, const float* __restrict__ deg){
  int node = blockIdx.x*4 + (threadIdx.x >> 6);
  int l = threadIdx.x & 63;
  int z = blockIdx.z;
  const float* xf = (z == 0) ? x0 : (z == 1) ? x1 : x2;
  const unsigned short* zin = zcat + z*ZSZE + 256;
  unsigned short* zout = zcat + z*ZSZE + (SRC == 0 ? 256 : 512);
  unsigned b0 = rowptr[node], b1 = rowptr[node + 1];
  float a0 = 0.f, a1 = 0.f, a2 = 0.f, a3 = 0.f;
  for (unsigned e = b0; e < b1; ++e){
    int s = csrc[e]; float w = csrw[e];
    if constexpr (SRC == 0){
      fvec4 v = *(const fvec4*)(xf + (long)s*256 + l*4);
      a0 += w*v[0]; a1 += w*v[1]; a2 += w*v[2]; a3 += w*v[3];
    } else {
      u16x4 v = *(const u16x4*)(zin + (long)s*768 + l*4);
      a0 += w*b2f(v[0]); a1 += w*b2f(v[1]); a2 += w*b2f(v[2]); a3 += w*b2f(v[3]);
    }
  }
  float dg = deg[node]; dg = dg > 1.f ? dg : 1.f;
  float inv = 1.f / dg;
  u16x4 o = { f2bf(a0*inv), f2bf(a1*inv), f2bf(a2*inv), f2bf(a3*inv) };
  *(u16x4*)(zout + (long)node*768 + l*4) = o;
}

// x (f32 [BN][256]) -> zcat cols 0:256 (bf16, row stride 768), z-batched
__global__ __launch_bounds__(256) void convx3_kernel(const float* __restrict__ x0,
    const float* __restrict__ x1, const float* __restrict__ x2,
    unsigned short* __restrict__ zcat){
  int id = blockIdx.x*256 + threadIdx.x;   // over 32768*64
  int z = blockIdx.z;
  const float* xf = (z == 0) ? x0 : (z == 1) ? x1 : x2;
  fvec4 v = ((const fvec4*)xf)[id];
  int m = id >> 6, c4 = id & 63;
  u16x4 o = { f2bf(v[0]), f2bf(v[1]), f2bf(v[2]), f2bf(v[3]) };
  *(u16x4*)(zcat + z*ZSZE + (long)m*768 + c4*4) = o;
}

// ---------------- weight prep ----------------
__global__ __launch_bounds__(256) void cvt_f2b_kernel(const float* __restrict__ s,
                                                      unsigned short* __restrict__ d, int n){
  int i = blockIdx.x*256 + threadIdx.x;
  if (i < n) d[i] = f2bf(s[i]);
}

// transpose+convert: src f32 [R][2^lgC] -> dst bf16 [2^lgC][R]
__global__ __launch_bounds__(256) void tcvt_kernel(const float* __restrict__ s,
    unsigned short* __restrict__ d, int lgC, int R){
  int id = blockIdx.x*256 + threadIdx.x;
  int r = id >> lgC, c = id & ((1 << lgC) - 1);
  d[(long)c*R + r] = f2bf(s[id]);
}

// Build BT[256][768], u/c INTERLEAVED: out-row n: j=n>>1; even n -> u_j
// (W_ru col 128+j), odd n -> c_j (W_c col j). k -> W row (k>>8)*384 + (k&255).
__global__ __launch_bounds__(256) void weff_kernel(const float* __restrict__ Wru,
    const float* __restrict__ bru, const float* __restrict__ Wc, const float* __restrict__ bc,
    unsigned short* __restrict__ Weff, float* __restrict__ beff){
  int id = blockIdx.x*256 + threadIdx.x;   // 256*768
  int n = id / 768, k = id % 768;
  int row = (k >> 8)*384 + (k & 255);
  int j = n >> 1;
  float w = ((n & 1) == 0) ? Wru[(long)row*256 + 128 + j] : Wc[(long)row*128 + j];
  Weff[(long)n*768 + k] = f2bf(w);
  if (k == 0) beff[n] = ((n & 1) == 0) ? bru[128 + j] : bc[j];
}

// PET4[(o>>2)*256 + b*4 + (o&3)] = pos_enc(b,o) + bhd[o]   (f32, [64]x[512] folded)
__global__ __launch_bounds__(256) void pe_kernel(const float* __restrict__ bhd,
                                                 float* __restrict__ PET4){
  int id = blockIdx.x*256 + threadIdx.x;   // 64*512
  int b = id >> 9, o = id & 511;
  float j2 = (float)(o & ~1);
  float ang = (float)b * expf(-j2 * (9.210340371976184f / 512.f)); // ln(1e4)
  float v = ((o & 1) ? cosf(ang) : sinf(ang)) + bhd[o];
  PET4[(o >> 2)*256 + b*4 + (o & 3)] = v;
}

// peq2[b][j] = bin[j] + sum_o PET(b,o) * Win[j][o]   (wave per j, lane = b)
__global__ __launch_bounds__(256) void peq2_kernel(const float* __restrict__ Win,
    const float* __restrict__ bin, const float* __restrict__ PET4, float* __restrict__ peq2){
  int j = blockIdx.x*4 + (threadIdx.x >> 6);
  int l = threadIdx.x & 63;
  float acc = 0.f;
  for (int o4 = 0; o4 < 128; ++o4){
    fvec4 wv = *(const fvec4*)(Win + (long)j*512 + o4*4);   // broadcast across lanes
    fvec4 pv = *(const fvec4*)(PET4 + o4*256 + l*4);        // coalesced
    acc += wv[0]*pv[0] + wv[1]*pv[1] + wv[2]*pv[2] + wv[3]*pv[3];
  }
  peq2[(long)l*1536 + j] = bin[j] + acc;
}

// beq[g] = bgate[g] + dot(Wgate[g,:], bout)
__global__ __launch_bounds__(128) void beq_kernel(const float* __restrict__ Wgt,
    const float* __restrict__ bout, const float* __restrict__ bgate, float* __restrict__ beq){
  int g = threadIdx.x;
  float s = bgate[g];
  for (int c = 0; c < 512; ++c) s += Wgt[(long)g*512 + c] * bout[c];
  beq[g] = s;
}

// ---------------- shared bf16 MFMA GEMM ----------------
// C[m][n] = scale * sum_k A[m][k]*Bt[n][k] (+bias) ; tiles 128x128, BK=64.
// Staging: global_load_lds width=16 (linear LDS dest = lane order).
// MODE 0: plain. MODE 1: attn scores. MODE 2: ctx (P@V^T). MODE 3: z-batched
//   plain (aOff=z*sA, bOff=z*sB, cOff=z*sC, bias+=z*256).
// EPI 0: f32. 2: bf16. 4: f32 + row remap (n,b)->(b*512+n).
// EPI 5: bf16 + per-(row&63) f32 row-table add (fused pe/bias for qkv).
// EPI 7: fused GRU: pair (u,c) via shfl_xor(1), store (1-sig(u))*tanh(c) f32.
template<int MODE, int EPI>
__global__ __launch_bounds__(256) void gemm_bt(
    const unsigned short* __restrict__ A, const unsigned short* __restrict__ Bt,
    float* __restrict__ Cf, unsigned short* __restrict__ Cb,
    int Ktot, int lda, int ldb, int ldc,
    long sA, long sB, long sC, int g0,
    const float* __restrict__ bias, const float* __restrict__ pe, float scale)
{
  __shared__ unsigned short As[128*64];
  __shared__ unsigned short Bs[128*64];
  const int tid = threadIdx.x;
  long aOff, bOff, cOff;
  if constexpr (MODE == 0 || MODE == 3){
    aOff = blockIdx.z * sA; bOff = blockIdx.z * sB; cOff = blockIdx.z * sC;
  } else if constexpr (MODE == 1){
    int g = g0 + blockIdx.z;
    long base = (long)(g >> 1)*1536 + (long)(g & 1)*256;
    aOff = base; bOff = base + 512; cOff = (long)blockIdx.z * 262144;
  } else {
    int g = g0 + blockIdx.z;
    aOff = (long)blockIdx.z * 262144;
    bOff = (long)g * 131072;
    cOff = (long)g * 256;
  }
  const int bm = blockIdx.y * 128, bn = blockIdx.x * 128;
  const int w = tid >> 6, l = tid & 63;
  const int wr = w >> 1, wc = w & 1;

  // per-lane global staging bases (element offsets); LDS dest is linear in c
  const unsigned short* aB[4];
  const unsigned short* bB[4];
  #pragma unroll
  for (int i = 0; i < 4; ++i){
    int c = tid + i*256;
    int row = c >> 3, gg = c & 7;
    aB[i] = A  + aOff + (long)(bm + row)*lda + gg*8;
    bB[i] = Bt + bOff + (long)(bn + row)*ldb + gg*8;
  }

  f32x4 acc[4][4] = {};
  for (int kt = 0; kt < Ktot; kt += 64){
    #pragma unroll
    for (int i = 0; i < 4; ++i){
      __builtin_amdgcn_global_load_lds(
        (const __attribute__((address_space(1))) unsigned int*)(aB[i] + kt),
        (__attribute__((address_space(3))) unsigned int*)&As[(i*256 + w*64)*8], 16, 0, 0);
      __builtin_amdgcn_global_load_lds(
        (const __attribute__((address_space(1))) unsigned int*)(bB[i] + kt),
        (__attribute__((address_space(3))) unsigned int*)&Bs[(i*256 + w*64)*8], 16, 0, 0);
    }
    __syncthreads();
    #pragma unroll
    for (int ks = 0; ks < 2; ++ks){
      bf16x8 aF[4], bF[4];
      #pragma unroll
      for (int mi = 0; mi < 4; ++mi)
        aF[mi] = *(const bf16x8*)(&As[(wr*64 + mi*16 + (l & 15))*64 + ks*32 + (l >> 4)*8]);
      #pragma unroll
      for (int ni = 0; ni < 4; ++ni)
        bF[ni] = *(const bf16x8*)(&Bs[(wc*64 + ni*16 + (l & 15))*64 + ks*32 + (l >> 4)*8]);
      #pragma unroll
      for (int mi = 0; mi < 4; ++mi)
        #pragma unroll
        for (int ni = 0; ni < 4; ++ni)
          acc[mi][ni] = __builtin_amdgcn_mfma_f32_16x16x32_bf16(aF[mi], bF[ni], acc[mi][ni], 0, 0, 0);
    }
    __syncthreads();
  }
  // D layout: col = lane&15, row = (lane>>4)*4 + j  (m89-verified)
  #pragma unroll
  for (int mi = 0; mi < 4; ++mi){
    #pragma unroll
    for (int ni = 0; ni < 4; ++ni){
      int col = bn + wc*64 + ni*16 + (l & 15);
      int row0 = bm + wr*64 + mi*16 + ((l >> 4) << 2);
      #pragma unroll
      for (int j = 0; j < 4; ++j){
        int row = row0 + j;
        float v = acc[mi][ni][j] * scale;
        if (bias){
          if constexpr (MODE == 3) v += bias[(int)blockIdx.z*256 + col];
          else v += bias[col];
        }
        if constexpr (EPI == 5) v += pe[((row & 63) * 1536) + col];
        if constexpr (EPI == 0){
          Cf[cOff + (long)row*ldc + col] = v;
        } else if constexpr (EPI == 4){
          long orow = (long)(row & 63)*512 + (row >> 6);
          Cf[orow*ldc + col] = v;
        } else if constexpr (EPI == 7){
          float other = __shfl_xor(v, 1);
          if (!(l & 1)){
            float uu = 1.f / (1.f + expf(-v));
            Cf[cOff + (long)row*ldc + (col >> 1)] = (1.f - uu) * tanhf(other);
          }
        } else {
          Cb[cOff + (long)row*ldc + col] = f2bf(v);
        }
      }
    }
  }
}

// ---------------- glue ----------------
// Afus[(n*64+b)][c] = fusion[b,c,n] = concat([hs,hl])[b*512 + 2c + (n>>8), n&255]
__global__ __launch_bounds__(256) void afus_kernel(const float* __restrict__ out,
                                                   unsigned short* __restrict__ Afus){
  int rc = blockIdx.x, a = blockIdx.y, b = blockIdx.z;
  int c = threadIdx.x;  // 0..255
  const float* hsrc = out + 2*OUTSEC;   // hs
  const float* hlrc = out + 1*OUTSEC;   // hl
  long rowb = (long)b*512 + 2*c + a;
  #pragma unroll 4
  for (int r0 = 0; r0 < 32; ++r0){
    int r = rc*32 + r0;
    float v = (r < 128) ? hsrc[rowb*128 + r] : hlrc[rowb*128 + (r - 128)];
    long mrow = (long)(a*256 + r)*64 + b;
    Afus[mrow*256 + c] = f2bf(v);
  }
}

// vT[g=(b,h)][d][t] = qkv[t*64+b][1024 + h*256 + d]  (64x64 LDS transpose tiles)
__global__ __launch_bounds__(256) void vt_kernel(const unsigned short* __restrict__ qkv,
                                                 unsigned short* __restrict__ vT){
  int g = blockIdx.y; int b = g >> 1, h = g & 1;
  int tt = blockIdx.x & 7, dt = blockIdx.x >> 3;
  __shared__ unsigned short sm[64][65];
  int lrow = threadIdx.x >> 6, lcol = threadIdx.x & 63;
  const unsigned short* src = qkv + (long)b*1536 + 1024 + (long)h*256 + dt*64;
  #pragma unroll
  for (int i = 0; i < 16; ++i){
    int t = tt*64 + lrow + i*4;
    sm[lrow + i*4][lcol] = src[(long)t*98304 + lcol];
  }
  __syncthreads();
  unsigned short* dstp = vT + (long)g*131072 + (long)(dt*64)*512 + tt*64;
  #pragma unroll
  for (int i = 0; i < 16; ++i){
    int d = lrow + i*4;
    dstp[(long)d*512 + lcol] = sm[lcol][d];
  }
}

// in-place row softmax over bf16 scores [65536 rows][512]
__global__ __launch_bounds__(256) void smax_kernel(unsigned short* __restrict__ S){
  long row = (long)blockIdx.x*4 + (threadIdx.x >> 6);
  int l = threadIdx.x & 63;
  unsigned short* p = S + row*512 + l*8;
  bf16x8 v = *(const bf16x8*)p;
  float f[8];
  #pragma unroll
  for (int j = 0; j < 8; ++j) f[j] = b2f((unsigned short)v[j]);
  float m = f[0];
  #pragma unroll
  for (int j = 1; j < 8; ++j) m = fmaxf(m, f[j]);
  #pragma unroll
  for (int off = 32; off; off >>= 1) m = fmaxf(m, __shfl_xor(m, off));
  float s = 0.f;
  #pragma unroll
  for (int j = 0; j < 8; ++j){ f[j] = expf(f[j] - m); s += f[j]; }
  #pragma unroll
  for (int off = 32; off; off >>= 1) s += __shfl_xor(s, off);
  float inv = 1.f / s;
  bf16x8 o;
  #pragma unroll
  for (int j = 0; j < 8; ++j) o[j] = (short)f2bf(f[j]*inv);
  *(bf16x8*)p = o;
}

// ---------------- host ----------------
extern "C" void kernel_launch(void* const* d_in, const int* in_sizes, int n_in,
                              void* d_out, int out_size, void* d_ws, size_t ws_size,
                              hipStream_t stream)
{
  (void)in_sizes; (void)n_in; (void)out_size;
  constexpr long MB = 1l << 20;
  if (ws_size < 200*MB) return;  // layout needs 200 MiB; fail loudly via absmax

  const float* x0 = (const float*)d_in[0];
  const float* x1 = (const float*)d_in[1];
  const float* x2 = (const float*)d_in[2];
  const int*   ei = (const int*)d_in[3];
  const float* ew = (const float*)d_in[4];
  const float* Wru[3] = {(const float*)d_in[5], (const float*)d_in[9],  (const float*)d_in[13]};
  const float* bru[3] = {(const float*)d_in[6], (const float*)d_in[10], (const float*)d_in[14]};
  const float* Wc[3]  = {(const float*)d_in[7], (const float*)d_in[11], (const float*)d_in[15]};
  const float* bc[3]  = {(const float*)d_in[8], (const float*)d_in[12], (const float*)d_in[16]};
  const float* Whd  = (const float*)d_in[17]; const float* bhd   = (const float*)d_in[18];
  const float* Win  = (const float*)d_in[19]; const float* bin   = (const float*)d_in[20];
  const float* Wout = (const float*)d_in[21]; const float* bout  = (const float*)d_in[22];
  const float* Wgt  = (const float*)d_in[23]; const float* bgate = (const float*)d_in[24];
  float* out = (float*)d_out;
  char* ws = (char*)d_ws;

  float*    deg    = (float*)(ws + 0);
  unsigned* cnt    = (unsigned*)(ws + 131072);
  unsigned* rowptr = (unsigned*)(ws + 262144);
  unsigned* curs   = (unsigned*)(ws + 524288);
  unsigned* csrc   = (unsigned*)(ws + 786432);
  float*    csrw   = (float*)(ws + 1835008);
  unsigned short* Weff = (unsigned short*)(ws + 2883584);   // 3 x [256][768]
  float*    beff   = (float*)(ws + 4063232);                // 3 x 256 f32
  float*    beq    = (float*)(ws + 4194304);                // 128 f32
  unsigned short* WIN   = (unsigned short*)(ws + 4456448);  // [1536][512] bf16
  unsigned short* WGTB  = (unsigned short*)(ws + 6029312);  // [128][512] bf16
  unsigned short* WHDT  = (unsigned short*)(ws + 6160384);  // [256][512] bf16 (Whd^T)
  unsigned short* WOUTT = (unsigned short*)(ws + 6422528);  // [512][512] bf16 (Wout^T)
  unsigned short* Wq2t  = (unsigned short*)(ws + 6946816);  // [1536][256] bf16 (Win*Whd)
  unsigned short* Weqt  = (unsigned short*)(ws + 7733248);  // [128][512] bf16 (Wgate*Wout)
  float*    PET4   = (float*)(ws + 7864320);                // [128][64][4] f32 (pe+bhd)^T
  float*    PEQ2   = (float*)(ws + 7995392);                // [64][1536] f32 (ends at 8MB)
  unsigned short* ZCAT3 = (unsigned short*)(ws + 40*MB);    // 3 x [32768][768] (40..184)
  unsigned short* AFUS  = (unsigned short*)(ws + 8*MB);     // [32768][256] 16MB (8..24)
  unsigned short* QKV   = (unsigned short*)(ws + 40*MB);    // [32768][1536] (40..136)
  unsigned short* VT    = (unsigned short*)(ws + 8*MB);     // [128][256][512] (8..40)
  unsigned short* SCOREB= (unsigned short*)(ws + 136*MB);   // [128][512][512] bf16 (136..200)
  unsigned short* CTX   = (unsigned short*)(ws + 40*MB);    // [512][32768] bf16 (40..72)

  // graph build
  hipMemsetAsync(deg,  0, 131072, stream);
  hipMemsetAsync(cnt,  0, 131072, stream);
  hipMemsetAsync(curs, 0, 131072, stream);
  histdeg_kernel<<<1024, 256, 0, stream>>>(ei, ew, cnt, deg);
  scan_kernel<<<1, 1024, 0, stream>>>(cnt, rowptr);
  scatter_kernel<<<1024, 256, 0, stream>>>(ei, ew, rowptr, curs, csrc, csrw);

  // weight prep
  for (int br = 0; br < 3; ++br)
    weff_kernel<<<768, 256, 0, stream>>>(Wru[br], bru[br], Wc[br], bc[br],
                                         Weff + (long)br*196608, beff + br*256);
  cvt_f2b_kernel<<<3072, 256, 0, stream>>>(Win, WIN,  786432);
  cvt_f2b_kernel<<<256,  256, 0, stream>>>(Wgt, WGTB, 65536);
  tcvt_kernel<<<512,  256, 0, stream>>>(Whd,  WHDT,  8, 512);   // [512][256] -> [256][512]
  tcvt_kernel<<<1024, 256, 0, stream>>>(Wout, WOUTT, 9, 512);   // [512][512] -> ^T
  pe_kernel<<<128, 256, 0, stream>>>(bhd, PET4);

  // fused-weight precompute
  gemm_bt<0,2><<<dim3(2,12,1), 256, 0, stream>>>(WIN, WHDT, nullptr, Wq2t,
      512, 512, 512, 256, 0,0,0, 0, nullptr, nullptr, 1.0f);
  gemm_bt<0,2><<<dim3(4,1,1), 256, 0, stream>>>(WGTB, WOUTT, nullptr, Weqt,
      512, 512, 512, 512, 0,0,0, 0, nullptr, nullptr, 1.0f);
  peq2_kernel<<<384, 256, 0, stream>>>(Win, bin, PET4, PEQ2);
  beq_kernel<<<1, 128, 0, stream>>>(Wgt, bout, bgate, beq);

  // branches (z-batched): hop features then fused GEMM+GRU-activation -> out 0..2
  convx3_kernel<<<dim3(8192,1,3), 256, 0, stream>>>(x0, x1, x2, ZCAT3);
  prop3_kernel<0><<<dim3(8192,1,3), 256, 0, stream>>>(x0, x1, x2, ZCAT3,
                                                      rowptr, csrc, csrw, deg);
  prop3_kernel<1><<<dim3(8192,1,3), 256, 0, stream>>>(x0, x1, x2, ZCAT3,
                                                      rowptr, csrc, csrw, deg);
  gemm_bt<3,7><<<dim3(2,256,3), 256, 0, stream>>>(ZCAT3, Weff, out, nullptr,
      768, 768, 768, 128, ZSZE, 196608, OUTSEC, 0, beff, nullptr, 1.0f);

  // fusion gather, then fused uh+qkv GEMM (K=256, pe/bias row-table in epilogue)
  afus_kernel<<<dim3(8,2,64), 256, 0, stream>>>(out, AFUS);
  gemm_bt<0,5><<<dim3(12,256,1), 256, 0, stream>>>(AFUS, Wq2t, nullptr, QKV,
      256, 256, 256, 1536, 0,0,0, 0, nullptr, PEQ2, 1.0f);
  vt_kernel<<<dim3(32,128), 256, 0, stream>>>(QKV, VT);

  // attention, single shot z=128: bf16 scores -> in-place softmax -> ctx
  gemm_bt<1,2><<<dim3(4,4,128), 256, 0, stream>>>(QKV, QKV, nullptr, SCOREB,
      256, 98304, 98304, 512, 0,0,0, 0, nullptr, nullptr, 0.0625f);
  smax_kernel<<<16384, 256, 0, stream>>>(SCOREB);
  gemm_bt<2,2><<<dim3(2,4,128), 256, 0, stream>>>(SCOREB, VT, nullptr, CTX,
      512, 512, 512, 32768, 0,0,0, 0, nullptr, nullptr, 1.0f);

  // fused wout+wgate output GEMM (row remap (n,b) -> b*512+n in epilogue)
  gemm_bt<0,4><<<dim3(1,256,1), 256, 0, stream>>>(CTX, Weqt, out + 3*OUTSEC, nullptr,
      512, 512, 512, 128, 0,0,0, 0, beq, nullptr, 1.0f);
}